// Round 7
// baseline (716.811 us; speedup 1.0000x reference)
//
#include <hip/hip_runtime.h>

typedef unsigned short u16;
typedef __attribute__((ext_vector_type(8))) short short8;
typedef __attribute__((ext_vector_type(4))) float float4v;

#define SCL2 (0.125f * 1.44269504088896340736f)   // logit scale folded into log2 domain
#define NEG_BIG -1.0e8f

static __device__ __forceinline__ u16 f2bf(float f) {
  union { float f; unsigned u; } x; x.f = f;
  unsigned r = x.u + 0x7fffu + ((x.u >> 16) & 1u);
  return (u16)(r >> 16);
}
static __device__ __forceinline__ float bf2f(u16 b) {
  union { unsigned u; float f; } x; x.u = ((unsigned)b) << 16;
  return x.f;
}
static __device__ __forceinline__ u16 f2h(float f) {
  union { u16 u; _Float16 h; } x; x.h = (_Float16)f; return x.u;
}

// ---------------------------------------------------------------------------
__global__ void detect_dtype(const unsigned* __restrict__ in0, int* __restrict__ flag) {
  if (threadIdx.x == 0 && blockIdx.x == 0) {
    int cnt = 0;
    for (int i = 0; i < 256; ++i) {
      unsigned e = (in0[i] >> 7) & 0xFFu;
      if (e >= 100u && e <= 140u) cnt++;
    }
    flag[0] = (cnt < 128) ? 1 : 0;
  }
}

// ---------------------------------------------------------------------------
// Fused converts: z=0 input(4M), z=1 memory(4M), z=2 pos_embs(2M) -> bf16
// ---------------------------------------------------------------------------
__global__ __launch_bounds__(256) void convert_all(
    const void* __restrict__ A0, const void* __restrict__ A1, const void* __restrict__ A2,
    u16* __restrict__ O0, u16* __restrict__ O1, u16* __restrict__ O2,
    const int* __restrict__ dflag) {
  int z = blockIdx.z;
  const void* in = (z == 0) ? A0 : (z == 1) ? A1 : A2;
  u16* out = (z == 0) ? O0 : (z == 1) ? O1 : O2;
  int n = (z == 2) ? 2048 * 1024 : 4 * 1024 * 1024;
  int i = (blockIdx.x * 256 + threadIdx.x) * 4;
  if (i >= n) return;
  if (dflag[0]) {
    float4 v = *(const float4*)((const float*)in + i);
    u16 o[4] = {f2bf(v.x), f2bf(v.y), f2bf(v.z), f2bf(v.w)};
    *(uint2*)(out + i) = *(uint2*)o;
  } else {
    *(uint2*)(out + i) = *(const uint2*)((const u16*)in + i);
  }
}

// ---------------------------------------------------------------------------
// Fused weight transposes (external dtype per flag) -> bf16 out[c][r]=in[r][c]
// ---------------------------------------------------------------------------
__global__ __launch_bounds__(256) void transpose_all(
    const void* __restrict__ W0, const void* __restrict__ W1,
    const void* __restrict__ W2, const void* __restrict__ W3,
    u16* __restrict__ O0, u16* __restrict__ O1,
    u16* __restrict__ O2, u16* __restrict__ O3,
    const int* __restrict__ dflag) {
  __shared__ __align__(16) u16 t[32][33];
  int z = blockIdx.z;
  const void* in = (z == 0) ? W0 : (z == 1) ? W1 : (z == 2) ? W2 : W3;
  u16* out = (z == 0) ? O0 : (z == 1) ? O1 : (z == 2) ? O2 : O3;
  int C = (z == 0) ? 2048 : 1024;
  if (blockIdx.x * 32 >= C) return;
  const int f32 = dflag[0];
  int c = blockIdx.x * 32 + threadIdx.x;
  int rbase = blockIdx.y * 32;
#pragma unroll
  for (int k = 0; k < 4; ++k) {
    int r = rbase + threadIdx.y + k * 8;
    size_t idx = (size_t)r * C + c;
    t[threadIdx.y + k * 8][threadIdx.x] =
        f32 ? f2bf(((const float*)in)[idx]) : ((const u16*)in)[idx];
  }
  __syncthreads();
  int r2 = rbase + threadIdx.x;
#pragma unroll
  for (int k = 0; k < 4; ++k) {
    int c2 = blockIdx.x * 32 + threadIdx.y + k * 8;
    out[(size_t)c2 * 1024 + r2] = t[threadIdx.x][threadIdx.y + k * 8];
  }
}

// ---------------------------------------------------------------------------
// bf16 GEMM: C[M,N] = A[M,K] @ BT[N,K]^T. 128x128 tile, 4 waves, BK=32,
// register-prefetch double-buffered staging (next k-tile loads issued right
// after the staging barrier; drain overlaps the MFMA phase).
// mode 0: bf16 C
// mode 1: dual bf16 C=acc+ub, C2=acc+vb (ub/vb external dtype per flag)
// mode 3: output store, dtype per flag
// mode 5: K/V split — cols<1024: bf16 Kb[rg*1024+cg]; cols>=1024: fp16
//         transposed V: C2[(cg-1024)*8192 + b*2048 + t] (packed 4-row stores)
// A==nullptr -> gather rows from [gmem;ginp] bf16 concat (rows = b*2048+t)
// ---------------------------------------------------------------------------
__global__ __launch_bounds__(256) void gemm_bt(
    const u16* __restrict__ A, int lda, long aOff, long aZ,
    const u16* __restrict__ BT, int ldb, long bOff, long bZ,
    void* __restrict__ Cp, int ldc, long cZ,
    int K, int mode,
    const u16* __restrict__ gmem, const u16* __restrict__ ginp,
    const void* __restrict__ ub, const void* __restrict__ vb,
    u16* __restrict__ C2, const int* __restrict__ dflag)
{
  __shared__ __align__(16) u16 As[128][40];
  __shared__ __align__(16) u16 Bs[128][40];
  const int f32g = dflag[0];
  const int tid = threadIdx.x;
  const int w = tid >> 6, lane = tid & 63, quad = lane >> 4, l15 = lane & 15;
  const int wr = w >> 1, wc = w & 1;
  const int m0 = blockIdx.y * 128, n0 = blockIdx.x * 128;
  const int z = blockIdx.z;
  const u16* Bb = BT + bOff + (long)z * bZ;
  const int srow = tid >> 2, sc8 = (tid & 3) * 8;

  float4v acc[4][4];
#pragma unroll
  for (int i = 0; i < 4; ++i)
#pragma unroll
    for (int j = 0; j < 4; ++j) acc[i][j] = (float4v){0.f, 0.f, 0.f, 0.f};

  uint4 aR[2], bR[2];
  auto loadK = [&](int kt) {
#pragma unroll
    for (int it = 0; it < 2; ++it) {
      int row = it * 64 + srow;
      const u16* ap;
      if (A) {
        ap = A + (size_t)(m0 + row) * lda + aOff + (long)z * aZ + kt + sc8;
      } else {
        int rg = m0 + row;
        int bb = rg >> 11, t = rg & 2047;
        ap = (t < 1024) ? (gmem + ((size_t)(bb * 1024 + t)) * 1024 + kt + sc8)
                        : (ginp + ((size_t)(bb * 1024 + t - 1024)) * 1024 + kt + sc8);
      }
      aR[it] = *(const uint4*)ap;
      bR[it] = *(const uint4*)(Bb + (size_t)(n0 + it * 64 + srow) * ldb + kt + sc8);
    }
  };
  loadK(0);

  for (int kt = 0; kt < K; kt += 32) {
#pragma unroll
    for (int it = 0; it < 2; ++it) {
      *(uint4*)&As[it * 64 + srow][sc8] = aR[it];
      *(uint4*)&Bs[it * 64 + srow][sc8] = bR[it];
    }
    __syncthreads();
    if (kt + 32 < K) loadK(kt + 32);
    short8 af[4], bf[4];
#pragma unroll
    for (int mi = 0; mi < 4; ++mi)
      af[mi] = *(const short8*)&As[wr * 64 + mi * 16 + l15][quad * 8];
#pragma unroll
    for (int ni = 0; ni < 4; ++ni)
      bf[ni] = *(const short8*)&Bs[wc * 64 + ni * 16 + l15][quad * 8];
#pragma unroll
    for (int mi = 0; mi < 4; ++mi)
#pragma unroll
      for (int ni = 0; ni < 4; ++ni)
        acc[mi][ni] = __builtin_amdgcn_mfma_f32_16x16x32_bf16(af[mi], bf[ni], acc[mi][ni], 0, 0, 0);
    __syncthreads();
  }

#pragma unroll
  for (int mi = 0; mi < 4; ++mi) {
#pragma unroll
    for (int ni = 0; ni < 4; ++ni) {
      int rg0 = m0 + wr * 64 + mi * 16 + quad * 4;
      int cg = n0 + wc * 64 + ni * 16 + l15;
      if (mode == 5 && cg >= 1024) {
        int d = cg - 1024, bb = rg0 >> 11, t0 = rg0 & 2047;
        u16 h4[4] = {f2h(acc[mi][ni][0]), f2h(acc[mi][ni][1]),
                     f2h(acc[mi][ni][2]), f2h(acc[mi][ni][3])};
        *(uint2*)&C2[(size_t)d * 8192 + bb * 2048 + t0] = *(uint2*)h4;
        continue;
      }
#pragma unroll
      for (int r = 0; r < 4; ++r) {
        int rg = rg0 + r;
        size_t ci = (size_t)rg * ldc + cg;
        float va = acc[mi][ni][r];
        if (mode == 0) {
          ((u16*)Cp + (long)z * cZ)[ci] = f2bf(va);
        } else if (mode == 1) {
          float uu = f32g ? ((const float*)ub)[cg] : bf2f(((const u16*)ub)[cg]);
          float vv = f32g ? ((const float*)vb)[cg] : bf2f(((const u16*)vb)[cg]);
          ((u16*)Cp)[ci] = f2bf(va + uu);
          C2[ci] = f2bf(va + vv);
        } else if (mode == 5) {
          ((u16*)Cp)[(size_t)rg * 1024 + cg] = f2bf(va);
        } else {  // mode 3
          if (f32g) ((float*)Cp)[ci] = va;
          else      ((u16*)Cp)[ci] = f2bf(va);
        }
      }
    }
  }
}

// ---------------------------------------------------------------------------
// Fused flash attention with in-tile positional band MFMA, register-prefetch
// double-buffered staging: next tile's 14 global loads (K/V/band) are issued
// immediately after the staging barrier and consumed (LDS write) at the top
// of the next iteration — the vmcnt drain overlaps a full tile of compute.
// Diagonal extraction uses source-side merge: 1 cndmask + 1 ds_bpermute.
// ---------------------------------------------------------------------------
__global__ __launch_bounds__(256, 2) void attn_fused(
    const u16* __restrict__ QU, const u16* __restrict__ QV,
    const u16* __restrict__ Kb, const u16* __restrict__ VT,
    const u16* __restrict__ Pb, u16* __restrict__ AWV)
{
  __shared__ __align__(16) u16 band[192 * 72];   // p-band; per-wave slices reused as Ps
  __shared__ __align__(16) u16 Ks[128][72];      // K tile [j][d] bf16
  __shared__ __align__(16) u16 Vs[64][136];      // V^T tile [d][j] fp16
  __shared__ __align__(16) u16 qvs[66][72];      // (q+v) rows [m0..m0+65] bf16
  const int b = blockIdx.z, h = blockIdx.y;
  const int i0 = (15 - blockIdx.x) * 64;         // big blocks first
  const int tid = threadIdx.x, w = tid >> 6, lane = tid & 63;
  const int quad = lane >> 4, l15 = lane & 15;
  const int iw = i0 + w * 16;
  const int m0 = b * 1024 + i0;
  const int MQ = 5120 - 1024 * b;                // dd <= MQ <=> unmasked

  // content-Q fragment (q+u)
  const size_t qb = ((size_t)(b * 1024 + iw + l15)) * 1024 + h * 64 + quad * 8;
  short8 qf0 = *(const short8*)(QU + qb);
  short8 qf1 = *(const short8*)(QU + qb + 32);

  // stage qv rows once per block (66 rows x 64 d)
#pragma unroll
  for (int it = 0; it < 3; ++it) {
    int slot = it * 256 + tid;
    if (slot < 528) {
      int row = slot >> 3, d8q = (slot & 7) * 8;
      int gr = m0 + row; if (gr > 4095) gr = 4095;   // tail rows never used in-mask
      *(uint4*)&qvs[row][d8q] = *(const uint4*)(QV + (size_t)gr * 1024 + h * 64 + d8q);
    }
  }

  float4v o[4];
#pragma unroll
  for (int ni = 0; ni < 4; ++ni) o[ni] = (float4v){0.f, 0.f, 0.f, 0.f};
  float mrun[4] = {NEG_BIG, NEG_BIG, NEG_BIG, NEG_BIG};
  float lrun[4] = {0.f, 0.f, 0.f, 0.f};

  const int toff = 48 - 16 * w;                  // wave band offset in block band
  const int nT = (i0 + 1088 + 127) / 128;

  // fixed per-thread staging slots (LDS addresses are jt-invariant)
  const int trow = tid >> 3, d8 = (tid & 7) * 8;   // band/Ks
  const int vd = tid >> 4, vj8 = (tid & 15) * 8;   // Vs

  uint4 bandR[6], ksR[4], vsR[4];
  auto loadTile = [&](int jt) {
    const int j0 = jt * 128;
    const int ddm = j0 + 4096 - m0 - 63;
#pragma unroll
    for (int it = 0; it < 6; ++it) {
      int t = it * 32 + trow;
      int dd = ddm + t;
      int q2 = (dd >= 2049) + (dd >= 4098);
      int jp = dd - 2049 * q2;
      int prow = (jp > 0) ? jp - 1 : 0;
      uint4 pv = *(const uint4*)(Pb + (size_t)prow * 1024 + h * 64 + d8);
      bandR[it] = (jp == 0) ? (uint4){0, 0, 0, 0} : pv;
    }
#pragma unroll
    for (int it = 0; it < 4; ++it) {
      int row = it * 32 + trow;
      ksR[it] = *(const uint4*)(Kb + ((size_t)(b * 2048 + j0 + row)) * 1024 + h * 64 + d8);
      int d = it * 16 + vd;
      vsR[it] = *(const uint4*)(VT + ((size_t)(h * 64 + d)) * 8192 + b * 2048 + j0 + vj8);
    }
  };
  loadTile(0);

  for (int jt = 0; jt < nT; ++jt) {
    const int j0 = jt * 128;
    const int ddminB = j0 + 4096 - (m0 + 63);

    // ---- LDS write phase (from prefetched registers) ----
#pragma unroll
    for (int it = 0; it < 6; ++it) *(uint4*)&band[(it * 32 + trow) * 72 + d8] = bandR[it];
#pragma unroll
    for (int it = 0; it < 4; ++it) {
      *(uint4*)&Ks[it * 32 + trow][d8] = ksR[it];
      *(uint4*)&Vs[it * 16 + vd][vj8] = vsR[it];
    }
    __syncthreads();

    // ---- issue next tile's global loads (drain overlaps this tile's compute) ----
    if (jt + 1 < nT) loadTile(jt + 1);

    // ---- content QK^T ----
    float4v sc[8];
#pragma unroll
    for (int nj = 0; nj < 8; ++nj) {
      short8 bk0 = *(const short8*)&Ks[nj * 16 + l15][quad * 8];
      short8 bk1 = *(const short8*)&Ks[nj * 16 + l15][32 + quad * 8];
      float4v s = (float4v){0.f, 0.f, 0.f, 0.f};
      s = __builtin_amdgcn_mfma_f32_16x16x32_bf16(qf0, bk0, s, 0, 0, 0);
      s = __builtin_amdgcn_mfma_f32_16x16x32_bf16(qf1, bk1, s, 0, 0, 0);
      sc[nj] = s;
    }

    // ---- positional band MFMA: wave's 16 rows x 144 cols ----
    const int ddminW = ddminB + toff;
    float4v bc[9];
    int q2c = -1;
    short8 a0, a1;
#pragma unroll
    for (int fc = 0; fc < 9; ++fc) {
      int dds = ddminW + fc * 16;
      int qlo = (dds >= 2049) + (dds >= 4098);
      int qhi = (dds + 15 >= 2049) + (dds + 15 >= 4098);
      if (qlo != q2c) {
        const u16* ar = &qvs[16 * w + l15 + qlo][0];
        a0 = *(const short8*)(ar + quad * 8);
        a1 = *(const short8*)(ar + 32 + quad * 8);
        q2c = qlo;
      }
      const u16* br = &band[(toff + fc * 16 + l15) * 72];
      short8 b0 = *(const short8*)(br + quad * 8);
      short8 b1 = *(const short8*)(br + 32 + quad * 8);
      float4v c = (float4v){0.f, 0.f, 0.f, 0.f};
      c = __builtin_amdgcn_mfma_f32_16x16x32_bf16(a0, b0, c, 0, 0, 0);
      c = __builtin_amdgcn_mfma_f32_16x16x32_bf16(a1, b1, c, 0, 0, 0);
      if (qhi != qlo) {  // threshold crosses inside this frag: redo with +1 row, merge
        const u16* ar2 = &qvs[16 * w + l15 + qhi][0];
        short8 e0 = *(const short8*)(ar2 + quad * 8);
        short8 e1 = *(const short8*)(ar2 + 32 + quad * 8);
        float4v c2 = (float4v){0.f, 0.f, 0.f, 0.f};
        c2 = __builtin_amdgcn_mfma_f32_16x16x32_bf16(e0, b0, c2, 0, 0, 0);
        c2 = __builtin_amdgcn_mfma_f32_16x16x32_bf16(e1, b1, c2, 0, 0, 0);
        int colX = ((qlo == 0) ? 2049 : 4098) - dds;   // 1..15
        bool useHi = (l15 >= colX);
#pragma unroll
        for (int rr = 0; rr < 4; ++rr) c[rr] = useHi ? c2[rr] : c[rr];
      }
      bc[fc] = c;
    }

    // ---- diagonal extraction: source-side merge + single bpermute ----
    const int tmaxW = MQ - ddminW;
#pragma unroll
    for (int r = 0; r < 4; ++r) {
      const int tb = 15 - quad * 4 - r;                      // in [0,15]
      const int adr = 4 * (((l15 + tb) & 15) + 16 * quad);   // source lane (same quad)
      const bool srcHi = (l15 < tb);  // this lane (as source) serves a hi-frag dest
#pragma unroll
      for (int nj = 0; nj < 8; ++nj) {
        float mg = srcHi ? bc[nj + 1][r] : bc[nj][r];
        int p = __builtin_amdgcn_ds_bpermute(adr, __float_as_int(mg));
        float pos = __int_as_float(p);
        float v2 = (sc[nj][r] + pos) * SCL2;
        int tw = nj * 16 + l15 + tb;
        sc[nj][r] = (tw <= tmaxW) ? v2 : NEG_BIG;
      }
    }
    __syncthreads();   // all band/Ks reads done; safe to overwrite band with Ps

    // ---- online softmax (log2 domain) ----
#pragma unroll
    for (int r = 0; r < 4; ++r) {
      float mx = sc[0][r];
#pragma unroll
      for (int nj = 1; nj < 8; ++nj) mx = fmaxf(mx, sc[nj][r]);
#pragma unroll
      for (int s = 1; s < 16; s <<= 1) mx = fmaxf(mx, __shfl_xor(mx, s, 64));
      float mnew = fmaxf(mrun[r], mx);
      float al = exp2f(mrun[r] - mnew);
      float rs = 0.f;
#pragma unroll
      for (int nj = 0; nj < 8; ++nj) {
        float pv = exp2f(sc[nj][r] - mnew);
        sc[nj][r] = pv;
        rs += pv;
      }
#pragma unroll
      for (int s = 1; s < 16; s <<= 1) rs += __shfl_xor(rs, s, 64);
      lrun[r] = lrun[r] * al + rs;
      mrun[r] = mnew;
#pragma unroll
      for (int ni = 0; ni < 4; ++ni) o[ni][r] *= al;
    }

    // ---- P pack (fp16, into per-wave slice of band area) + PV ----
    u16* Psw = band + w * 1152;   // [16][72]
#pragma unroll
    for (int hk = 0; hk < 2; ++hk) {
#pragma unroll
      for (int nj = 0; nj < 4; ++nj)
#pragma unroll
        for (int r = 0; r < 4; ++r)
          Psw[(quad * 4 + r) * 72 + nj * 16 + l15] = f2h(sc[hk * 4 + nj][r]);
      // same-wave LDS write->read: DS pipe is in-order per wave
#pragma unroll
      for (int kc = 0; kc < 2; ++kc) {
        short8 ap = *(const short8*)&Psw[l15 * 72 + kc * 32 + quad * 8];
#pragma unroll
        for (int ni = 0; ni < 4; ++ni) {
          short8 bv = *(const short8*)&Vs[ni * 16 + l15][hk * 64 + kc * 32 + quad * 8];
          o[ni] = __builtin_amdgcn_mfma_f32_16x16x32_f16(ap, bv, o[ni], 0, 0, 0);
        }
      }
    }
    __syncthreads();
  }

#pragma unroll
  for (int r = 0; r < 4; ++r) {
    float inv = 1.0f / lrun[r];
#pragma unroll
    for (int ni = 0; ni < 4; ++ni) {
      AWV[((size_t)(b * 1024 + iw + quad * 4 + r)) * 1024 + h * 64 + ni * 16 + l15] =
          f2bf(o[ni][r] * inv);
    }
  }
}

// ---------------------------------------------------------------------------
extern "C" void kernel_launch(void* const* d_in, const int* in_sizes, int n_in,
                              void* d_out, int out_size, void* d_ws, size_t ws_size,
                              hipStream_t stream) {
  const void* input_ = d_in[0];
  const void* pose   = d_in[1];
  const void* memry  = d_in[2];
  const void* ubias  = d_in[3];
  const void* vbias  = d_in[4];
  const void* Wkv    = d_in[5];
  const void* Wq     = d_in[6];
  const void* Wp     = d_in[7];
  const void* Wout   = d_in[8];
  // d_in[9] (mask) unused: mask is j <= i + 1024, computed analytically.

  char* base = (char*)d_ws;
  size_t off = 0;
  auto carve = [&](size_t bytes) {
    void* r = base + off;
    off += (bytes + 255) & ~(size_t)255;
    return r;
  };
  int* dflag = (int*)carve(256);
  u16* Kb    = (u16*)carve((size_t)4 * 2048 * 1024 * 2);   // K  [b][t][hd] bf16
  u16* VT    = (u16*)carve((size_t)1024 * 4 * 2048 * 2);   // V^T [hd][b][t] fp16
  u16* QU    = (u16*)carve((size_t)4 * 1024 * 1024 * 2);
  u16* QV    = (u16*)carve((size_t)4 * 1024 * 1024 * 2);
  u16* Pb    = (u16*)carve((size_t)2048 * 1024 * 2);
  u16* AWVb  = (u16*)carve((size_t)4 * 1024 * 1024 * 2);
  u16* WkvT  = (u16*)carve((size_t)2048 * 1024 * 2);
  u16* WqT   = (u16*)carve((size_t)1024 * 1024 * 2);
  u16* WpT   = (u16*)carve((size_t)1024 * 1024 * 2);
  u16* WoutT = (u16*)carve((size_t)1024 * 1024 * 2);
  u16* inpB  = (u16*)carve((size_t)4 * 1024 * 1024 * 2);
  u16* memB  = (u16*)carve((size_t)4 * 1024 * 1024 * 2);
  u16* poseB = (u16*)carve((size_t)2048 * 1024 * 2);

  detect_dtype<<<1, 64, 0, stream>>>((const unsigned*)input_, dflag);
  convert_all<<<dim3(4096, 1, 3), 256, 0, stream>>>(
      input_, memry, pose, inpB, memB, poseB, dflag);
  transpose_all<<<dim3(64, 32, 4), dim3(32, 8), 0, stream>>>(
      Wkv, Wq, Wp, Wout, WkvT, WqT, WpT, WoutT, dflag);

  // kv = [memory;input] @ W_kv  (M=8192, N=2048, K=1024) — K->Kb bf16, V->VT fp16^T
  gemm_bt<<<dim3(16, 64, 1), 256, 0, stream>>>(
      nullptr, 0, 0, 0, WkvT, 1024, 0, 0, Kb, 1024, 0, 1024, 5,
      memB, inpB, nullptr, nullptr, VT, dflag);
  // q = input @ W_q, fused +u/+v -> QU, QV  (M=4096, N=1024, K=1024)
  gemm_bt<<<dim3(8, 32, 1), 256, 0, stream>>>(
      inpB, 1024, 0, 0, WqT, 1024, 0, 0, QU, 1024, 0, 1024, 1,
      nullptr, nullptr, ubias, vbias, QV, dflag);
  // p = pos_embs @ W_p  (M=2048, N=1024, K=1024)
  gemm_bt<<<dim3(8, 16, 1), 256, 0, stream>>>(
      poseB, 1024, 0, 0, WpT, 1024, 0, 0, Pb, 1024, 0, 1024, 0,
      nullptr, nullptr, nullptr, nullptr, nullptr, dflag);

  // fused attention, all 16 heads in one dispatch (1024 blocks)
  attn_fused<<<dim3(16, 16, 4), 256, 0, stream>>>(QU, QV, Kb, VT, Pb, AWVb);

  // out = awv @ W_out  (M=4096, N=1024, K=1024), output dtype per flag
  gemm_bt<<<dim3(8, 32, 1), 256, 0, stream>>>(
      AWVb, 1024, 0, 0, WoutT, 1024, 0, 0, d_out, 1024, 0, 1024, 3,
      nullptr, nullptr, nullptr, nullptr, nullptr, dflag);
}

// Round 8
// 475.129 us; speedup vs baseline: 1.5087x; 1.5087x over previous
//
#include <hip/hip_runtime.h>

typedef unsigned short u16;
typedef __attribute__((ext_vector_type(8))) short short8;
typedef __attribute__((ext_vector_type(4))) float float4v;

#define SCL2 (0.125f * 1.44269504088896340736f)   // logit scale folded into log2 domain
#define NEG_BIG -1.0e8f

static __device__ __forceinline__ u16 f2bf(float f) {
  union { float f; unsigned u; } x; x.f = f;
  unsigned r = x.u + 0x7fffu + ((x.u >> 16) & 1u);
  return (u16)(r >> 16);
}
static __device__ __forceinline__ float bf2f(u16 b) {
  union { unsigned u; float f; } x; x.u = ((unsigned)b) << 16;
  return x.f;
}
static __device__ __forceinline__ u16 f2h(float f) {
  union { u16 u; _Float16 h; } x; x.h = (_Float16)f; return x.u;
}

// ---------------------------------------------------------------------------
__global__ void detect_dtype(const unsigned* __restrict__ in0, int* __restrict__ flag) {
  if (threadIdx.x == 0 && blockIdx.x == 0) {
    int cnt = 0;
    for (int i = 0; i < 256; ++i) {
      unsigned e = (in0[i] >> 7) & 0xFFu;
      if (e >= 100u && e <= 140u) cnt++;
    }
    flag[0] = (cnt < 128) ? 1 : 0;
  }
}

// ---------------------------------------------------------------------------
// Fused converts: z=0 input(4M), z=1 memory(4M), z=2 pos_embs(2M) -> bf16
// ---------------------------------------------------------------------------
__global__ __launch_bounds__(256) void convert_all(
    const void* __restrict__ A0, const void* __restrict__ A1, const void* __restrict__ A2,
    u16* __restrict__ O0, u16* __restrict__ O1, u16* __restrict__ O2,
    const int* __restrict__ dflag) {
  int z = blockIdx.z;
  const void* in = (z == 0) ? A0 : (z == 1) ? A1 : A2;
  u16* out = (z == 0) ? O0 : (z == 1) ? O1 : O2;
  int n = (z == 2) ? 2048 * 1024 : 4 * 1024 * 1024;
  int i = (blockIdx.x * 256 + threadIdx.x) * 4;
  if (i >= n) return;
  if (dflag[0]) {
    float4 v = *(const float4*)((const float*)in + i);
    u16 o[4] = {f2bf(v.x), f2bf(v.y), f2bf(v.z), f2bf(v.w)};
    *(uint2*)(out + i) = *(uint2*)o;
  } else {
    *(uint2*)(out + i) = *(const uint2*)((const u16*)in + i);
  }
}

// ---------------------------------------------------------------------------
// Fused weight transposes (external dtype per flag) -> bf16 out[c][r]=in[r][c]
// ---------------------------------------------------------------------------
__global__ __launch_bounds__(256) void transpose_all(
    const void* __restrict__ W0, const void* __restrict__ W1,
    const void* __restrict__ W2, const void* __restrict__ W3,
    u16* __restrict__ O0, u16* __restrict__ O1,
    u16* __restrict__ O2, u16* __restrict__ O3,
    const int* __restrict__ dflag) {
  __shared__ __align__(16) u16 t[32][33];
  int z = blockIdx.z;
  const void* in = (z == 0) ? W0 : (z == 1) ? W1 : (z == 2) ? W2 : W3;
  u16* out = (z == 0) ? O0 : (z == 1) ? O1 : (z == 2) ? O2 : O3;
  int C = (z == 0) ? 2048 : 1024;
  if (blockIdx.x * 32 >= C) return;
  const int f32 = dflag[0];
  int c = blockIdx.x * 32 + threadIdx.x;
  int rbase = blockIdx.y * 32;
#pragma unroll
  for (int k = 0; k < 4; ++k) {
    int r = rbase + threadIdx.y + k * 8;
    size_t idx = (size_t)r * C + c;
    t[threadIdx.y + k * 8][threadIdx.x] =
        f32 ? f2bf(((const float*)in)[idx]) : ((const u16*)in)[idx];
  }
  __syncthreads();
  int r2 = rbase + threadIdx.x;
#pragma unroll
  for (int k = 0; k < 4; ++k) {
    int c2 = blockIdx.x * 32 + threadIdx.y + k * 8;
    out[(size_t)c2 * 1024 + r2] = t[threadIdx.x][threadIdx.y + k * 8];
  }
}

// row pointer for A (or gathered [gmem;ginp] concat when A==nullptr)
static __device__ __forceinline__ const u16* gemm_arow(
    const u16* A, const u16* gmem, const u16* ginp,
    int lda, long aOff, long aZ, int z, int rg) {
  if (A) return A + (size_t)rg * lda + aOff + (long)z * aZ;
  int bb = rg >> 11, t = rg & 2047;
  return (t < 1024) ? (gmem + ((size_t)(bb * 1024 + t)) * 1024)
                    : (ginp + ((size_t)(bb * 1024 + t - 1024)) * 1024);
}

// ---------------------------------------------------------------------------
// bf16 GEMM: C[M,N] = A[M,K] @ BT[N,K]^T. 128x128 tile, 4 waves, BK=32.
// Register-prefetch double-buffer with NAMED uint4 scalars (spill-proof; the
// round-7 lambda/array version lived in scratch — 386 MB of spill traffic).
// modes as before (0/1/3/5).
// ---------------------------------------------------------------------------
__global__ __launch_bounds__(256) void gemm_bt(
    const u16* __restrict__ A, int lda, long aOff, long aZ,
    const u16* __restrict__ BT, int ldb, long bOff, long bZ,
    void* __restrict__ Cp, int ldc, long cZ,
    int K, int mode,
    const u16* __restrict__ gmem, const u16* __restrict__ ginp,
    const void* __restrict__ ub, const void* __restrict__ vb,
    u16* __restrict__ C2, const int* __restrict__ dflag)
{
  __shared__ __align__(16) u16 As[128][40];
  __shared__ __align__(16) u16 Bs[128][40];
  const int f32g = dflag[0];
  const int tid = threadIdx.x;
  const int w = tid >> 6, lane = tid & 63, quad = lane >> 4, l15 = lane & 15;
  const int wr = w >> 1, wc = w & 1;
  const int m0 = blockIdx.y * 128, n0 = blockIdx.x * 128;
  const int z = blockIdx.z;
  const u16* Bb = BT + bOff + (long)z * bZ;
  const int srow = tid >> 2, sc8 = (tid & 3) * 8;

  // loop-invariant row pointers
  const u16* apr0 = gemm_arow(A, gmem, ginp, lda, aOff, aZ, z, m0 + srow) + sc8;
  const u16* apr1 = gemm_arow(A, gmem, ginp, lda, aOff, aZ, z, m0 + 64 + srow) + sc8;
  const u16* bpr0 = Bb + (size_t)(n0 + srow) * ldb + sc8;
  const u16* bpr1 = Bb + (size_t)(n0 + 64 + srow) * ldb + sc8;

  float4v acc[4][4];
#pragma unroll
  for (int i = 0; i < 4; ++i)
#pragma unroll
    for (int j = 0; j < 4; ++j) acc[i][j] = (float4v){0.f, 0.f, 0.f, 0.f};

  uint4 aR0 = *(const uint4*)(apr0);
  uint4 aR1 = *(const uint4*)(apr1);
  uint4 bR0 = *(const uint4*)(bpr0);
  uint4 bR1 = *(const uint4*)(bpr1);

  for (int kt = 0; kt < K; kt += 32) {
    *(uint4*)&As[srow][sc8] = aR0;
    *(uint4*)&As[64 + srow][sc8] = aR1;
    *(uint4*)&Bs[srow][sc8] = bR0;
    *(uint4*)&Bs[64 + srow][sc8] = bR1;
    __syncthreads();
    if (kt + 32 < K) {
      aR0 = *(const uint4*)(apr0 + kt + 32);
      aR1 = *(const uint4*)(apr1 + kt + 32);
      bR0 = *(const uint4*)(bpr0 + kt + 32);
      bR1 = *(const uint4*)(bpr1 + kt + 32);
    }
    short8 af[4], bf[4];
#pragma unroll
    for (int mi = 0; mi < 4; ++mi)
      af[mi] = *(const short8*)&As[wr * 64 + mi * 16 + l15][quad * 8];
#pragma unroll
    for (int ni = 0; ni < 4; ++ni)
      bf[ni] = *(const short8*)&Bs[wc * 64 + ni * 16 + l15][quad * 8];
#pragma unroll
    for (int mi = 0; mi < 4; ++mi)
#pragma unroll
      for (int ni = 0; ni < 4; ++ni)
        acc[mi][ni] = __builtin_amdgcn_mfma_f32_16x16x32_bf16(af[mi], bf[ni], acc[mi][ni], 0, 0, 0);
    __syncthreads();
  }

#pragma unroll
  for (int mi = 0; mi < 4; ++mi) {
#pragma unroll
    for (int ni = 0; ni < 4; ++ni) {
      int rg0 = m0 + wr * 64 + mi * 16 + quad * 4;
      int cg = n0 + wc * 64 + ni * 16 + l15;
      if (mode == 5 && cg >= 1024) {
        int d = cg - 1024, bb = rg0 >> 11, t0 = rg0 & 2047;
        u16 h4[4] = {f2h(acc[mi][ni][0]), f2h(acc[mi][ni][1]),
                     f2h(acc[mi][ni][2]), f2h(acc[mi][ni][3])};
        *(uint2*)&C2[(size_t)d * 8192 + bb * 2048 + t0] = *(uint2*)h4;
        continue;
      }
#pragma unroll
      for (int r = 0; r < 4; ++r) {
        int rg = rg0 + r;
        size_t ci = (size_t)rg * ldc + cg;
        float va = acc[mi][ni][r];
        if (mode == 0) {
          ((u16*)Cp + (long)z * cZ)[ci] = f2bf(va);
        } else if (mode == 1) {
          float uu = f32g ? ((const float*)ub)[cg] : bf2f(((const u16*)ub)[cg]);
          float vv = f32g ? ((const float*)vb)[cg] : bf2f(((const u16*)vb)[cg]);
          ((u16*)Cp)[ci] = f2bf(va + uu);
          C2[ci] = f2bf(va + vv);
        } else if (mode == 5) {
          ((u16*)Cp)[(size_t)rg * 1024 + cg] = f2bf(va);
        } else {  // mode 3
          if (f32g) ((float*)Cp)[ci] = va;
          else      ((u16*)Cp)[ci] = f2bf(va);
        }
      }
    }
  }
}

// band-element load: resolves rel-shift row for column dd, zero at jp==0
#define BLD(itc) ({ \
  int dd_ = ddmN + (itc) * 32 + trow; \
  int q2_ = (dd_ >= 2049) + (dd_ >= 4098); \
  int jp_ = dd_ - 2049 * q2_; \
  uint4 pv_ = *(const uint4*)(PbH + (size_t)((jp_ > 0) ? jp_ - 1 : 0) * 1024); \
  uint4 z4_ = {0u, 0u, 0u, 0u}; \
  (jp_ == 0) ? z4_ : pv_; })

// ---------------------------------------------------------------------------
// Fused flash attention with in-tile positional band MFMA + spill-proof
// register-prefetch double-buffer (named uint4 scalars, hoisted pointers).
// ---------------------------------------------------------------------------
__global__ __launch_bounds__(256, 2) void attn_fused(
    const u16* __restrict__ QU, const u16* __restrict__ QV,
    const u16* __restrict__ Kb, const u16* __restrict__ VT,
    const u16* __restrict__ Pb, u16* __restrict__ AWV)
{
  __shared__ __align__(16) u16 band[192 * 72];   // p-band; per-wave slices reused as Ps
  __shared__ __align__(16) u16 Ks[128][72];      // K tile [j][d] bf16
  __shared__ __align__(16) u16 Vs[64][136];      // V^T tile [d][j] fp16
  __shared__ __align__(16) u16 qvs[66][72];      // (q+v) rows [m0..m0+65] bf16
  const int b = blockIdx.z, h = blockIdx.y;
  const int i0 = (15 - blockIdx.x) * 64;         // big blocks first
  const int tid = threadIdx.x, w = tid >> 6, lane = tid & 63;
  const int quad = lane >> 4, l15 = lane & 15;
  const int iw = i0 + w * 16;
  const int m0 = b * 1024 + i0;
  const int MQ = 5120 - 1024 * b;                // dd <= MQ <=> unmasked

  // content-Q fragment (q+u)
  const size_t qb = ((size_t)(b * 1024 + iw + l15)) * 1024 + h * 64 + quad * 8;
  short8 qf0 = *(const short8*)(QU + qb);
  short8 qf1 = *(const short8*)(QU + qb + 32);

  // stage qv rows once per block (66 rows x 64 d)
#pragma unroll
  for (int it = 0; it < 3; ++it) {
    int slot = it * 256 + tid;
    if (slot < 528) {
      int row = slot >> 3, d8q = (slot & 7) * 8;
      int gr = m0 + row; if (gr > 4095) gr = 4095;   // tail rows never used in-mask
      *(uint4*)&qvs[row][d8q] = *(const uint4*)(QV + (size_t)gr * 1024 + h * 64 + d8q);
    }
  }

  float4v o[4];
#pragma unroll
  for (int ni = 0; ni < 4; ++ni) o[ni] = (float4v){0.f, 0.f, 0.f, 0.f};
  float mrun[4] = {NEG_BIG, NEG_BIG, NEG_BIG, NEG_BIG};
  float lrun[4] = {0.f, 0.f, 0.f, 0.f};

  const int toff = 48 - 16 * w;                  // wave band offset in block band
  const int nT = (i0 + 1088 + 127) / 128;

  // fixed per-thread staging slots + hoisted base pointers
  const int trow = tid >> 3, d8 = (tid & 7) * 8;   // band/Ks
  const int vd = tid >> 4, vj8 = (tid & 15) * 8;   // Vs
  const u16* PbH = Pb + h * 64 + d8;
  const u16* KbH = Kb + ((size_t)(b * 2048 + trow)) * 1024 + h * 64 + d8;
  const u16* VtH = VT + ((size_t)(h * 64 + vd)) * 8192 + b * 2048 + vj8;
  const int ddm0 = 4096 - m0 - 63 + trow;          // dd at (j0=0, it=0)

  // ---- prologue: prefetch tile 0 into named registers ----
  int ddmN = ddm0 - trow;   // BLD adds trow back
  uint4 bRa = BLD(0), bRb = BLD(1), bRc = BLD(2), bRd = BLD(3), bRe = BLD(4), bRf = BLD(5);
  uint4 kRa = *(const uint4*)(KbH);
  uint4 kRb = *(const uint4*)(KbH + 32 * 1024);
  uint4 kRc = *(const uint4*)(KbH + 64 * 1024);
  uint4 kRd = *(const uint4*)(KbH + 96 * 1024);
  uint4 vRa = *(const uint4*)(VtH);
  uint4 vRb = *(const uint4*)(VtH + 16 * 8192);
  uint4 vRc = *(const uint4*)(VtH + 32 * 8192);
  uint4 vRd = *(const uint4*)(VtH + 48 * 8192);

  for (int jt = 0; jt < nT; ++jt) {
    const int j0 = jt * 128;
    const int ddminB = j0 + 4096 - (m0 + 63);

    // ---- LDS write phase (from prefetched registers) ----
    *(uint4*)&band[(0 * 32 + trow) * 72 + d8] = bRa;
    *(uint4*)&band[(1 * 32 + trow) * 72 + d8] = bRb;
    *(uint4*)&band[(2 * 32 + trow) * 72 + d8] = bRc;
    *(uint4*)&band[(3 * 32 + trow) * 72 + d8] = bRd;
    *(uint4*)&band[(4 * 32 + trow) * 72 + d8] = bRe;
    *(uint4*)&band[(5 * 32 + trow) * 72 + d8] = bRf;
    *(uint4*)&Ks[0 * 32 + trow][d8] = kRa;
    *(uint4*)&Ks[1 * 32 + trow][d8] = kRb;
    *(uint4*)&Ks[2 * 32 + trow][d8] = kRc;
    *(uint4*)&Ks[3 * 32 + trow][d8] = kRd;
    *(uint4*)&Vs[0 * 16 + vd][vj8] = vRa;
    *(uint4*)&Vs[1 * 16 + vd][vj8] = vRb;
    *(uint4*)&Vs[2 * 16 + vd][vj8] = vRc;
    *(uint4*)&Vs[3 * 16 + vd][vj8] = vRd;
    __syncthreads();

    // ---- issue next tile's loads (drain overlaps this tile's compute) ----
    if (jt + 1 < nT) {
      const int j0n = j0 + 128;
      ddmN = j0n + 4096 - m0 - 63;
      bRa = BLD(0); bRb = BLD(1); bRc = BLD(2);
      bRd = BLD(3); bRe = BLD(4); bRf = BLD(5);
      const u16* kp = KbH + (size_t)j0n * 1024;
      kRa = *(const uint4*)(kp);
      kRb = *(const uint4*)(kp + 32 * 1024);
      kRc = *(const uint4*)(kp + 64 * 1024);
      kRd = *(const uint4*)(kp + 96 * 1024);
      const u16* vp = VtH + j0n;
      vRa = *(const uint4*)(vp);
      vRb = *(const uint4*)(vp + 16 * 8192);
      vRc = *(const uint4*)(vp + 32 * 8192);
      vRd = *(const uint4*)(vp + 48 * 8192);
    }

    // ---- content QK^T ----
    float4v sc[8];
#pragma unroll
    for (int nj = 0; nj < 8; ++nj) {
      short8 bk0 = *(const short8*)&Ks[nj * 16 + l15][quad * 8];
      short8 bk1 = *(const short8*)&Ks[nj * 16 + l15][32 + quad * 8];
      float4v s = (float4v){0.f, 0.f, 0.f, 0.f};
      s = __builtin_amdgcn_mfma_f32_16x16x32_bf16(qf0, bk0, s, 0, 0, 0);
      s = __builtin_amdgcn_mfma_f32_16x16x32_bf16(qf1, bk1, s, 0, 0, 0);
      sc[nj] = s;
    }

    // ---- positional band MFMA: wave's 16 rows x 144 cols ----
    const int ddminW = ddminB + toff;
    float4v bc[9];
    int q2c = -1;
    short8 a0, a1;
#pragma unroll
    for (int fc = 0; fc < 9; ++fc) {
      int dds = ddminW + fc * 16;
      int qlo = (dds >= 2049) + (dds >= 4098);
      int qhi = (dds + 15 >= 2049) + (dds + 15 >= 4098);
      if (qlo != q2c) {
        const u16* ar = &qvs[16 * w + l15 + qlo][0];
        a0 = *(const short8*)(ar + quad * 8);
        a1 = *(const short8*)(ar + 32 + quad * 8);
        q2c = qlo;
      }
      const u16* br = &band[(toff + fc * 16 + l15) * 72];
      short8 b0 = *(const short8*)(br + quad * 8);
      short8 b1 = *(const short8*)(br + 32 + quad * 8);
      float4v c = (float4v){0.f, 0.f, 0.f, 0.f};
      c = __builtin_amdgcn_mfma_f32_16x16x32_bf16(a0, b0, c, 0, 0, 0);
      c = __builtin_amdgcn_mfma_f32_16x16x32_bf16(a1, b1, c, 0, 0, 0);
      if (qhi != qlo) {  // threshold crosses inside this frag: redo with +1 row, merge
        const u16* ar2 = &qvs[16 * w + l15 + qhi][0];
        short8 e0 = *(const short8*)(ar2 + quad * 8);
        short8 e1 = *(const short8*)(ar2 + 32 + quad * 8);
        float4v c2 = (float4v){0.f, 0.f, 0.f, 0.f};
        c2 = __builtin_amdgcn_mfma_f32_16x16x32_bf16(e0, b0, c2, 0, 0, 0);
        c2 = __builtin_amdgcn_mfma_f32_16x16x32_bf16(e1, b1, c2, 0, 0, 0);
        int colX = ((qlo == 0) ? 2049 : 4098) - dds;   // 1..15
        bool useHi = (l15 >= colX);
#pragma unroll
        for (int rr = 0; rr < 4; ++rr) c[rr] = useHi ? c2[rr] : c[rr];
      }
      bc[fc] = c;
    }

    // ---- diagonal extraction: source-side merge + single bpermute ----
    const int tmaxW = MQ - ddminW;
#pragma unroll
    for (int r = 0; r < 4; ++r) {
      const int tb = 15 - quad * 4 - r;                      // in [0,15]
      const int adr = 4 * (((l15 + tb) & 15) + 16 * quad);   // source lane (same quad)
      const bool srcHi = (l15 < tb);  // this lane (as source) serves a hi-frag dest
#pragma unroll
      for (int nj = 0; nj < 8; ++nj) {
        float mg = srcHi ? bc[nj + 1][r] : bc[nj][r];
        int p = __builtin_amdgcn_ds_bpermute(adr, __float_as_int(mg));
        float pos = __int_as_float(p);
        float v2 = (sc[nj][r] + pos) * SCL2;
        int tw = nj * 16 + l15 + tb;
        sc[nj][r] = (tw <= tmaxW) ? v2 : NEG_BIG;
      }
    }
    __syncthreads();   // all band/Ks reads done; safe to overwrite band with Ps

    // ---- online softmax (log2 domain) ----
#pragma unroll
    for (int r = 0; r < 4; ++r) {
      float mx = sc[0][r];
#pragma unroll
      for (int nj = 1; nj < 8; ++nj) mx = fmaxf(mx, sc[nj][r]);
#pragma unroll
      for (int s = 1; s < 16; s <<= 1) mx = fmaxf(mx, __shfl_xor(mx, s, 64));
      float mnew = fmaxf(mrun[r], mx);
      float al = exp2f(mrun[r] - mnew);
      float rs = 0.f;
#pragma unroll
      for (int nj = 0; nj < 8; ++nj) {
        float pv = exp2f(sc[nj][r] - mnew);
        sc[nj][r] = pv;
        rs += pv;
      }
#pragma unroll
      for (int s = 1; s < 16; s <<= 1) rs += __shfl_xor(rs, s, 64);
      lrun[r] = lrun[r] * al + rs;
      mrun[r] = mnew;
#pragma unroll
      for (int ni = 0; ni < 4; ++ni) o[ni][r] *= al;
    }

    // ---- P pack (fp16, into per-wave slice of band area) + PV ----
    u16* Psw = band + w * 1152;   // [16][72]
#pragma unroll
    for (int hk = 0; hk < 2; ++hk) {
#pragma unroll
      for (int nj = 0; nj < 4; ++nj)
#pragma unroll
        for (int r = 0; r < 4; ++r)
          Psw[(quad * 4 + r) * 72 + nj * 16 + l15] = f2h(sc[hk * 4 + nj][r]);
      // same-wave LDS write->read: DS pipe is in-order per wave
#pragma unroll
      for (int kc = 0; kc < 2; ++kc) {
        short8 ap = *(const short8*)&Psw[l15 * 72 + kc * 32 + quad * 8];
#pragma unroll
        for (int ni = 0; ni < 4; ++ni) {
          short8 bv = *(const short8*)&Vs[ni * 16 + l15][hk * 64 + kc * 32 + quad * 8];
          o[ni] = __builtin_amdgcn_mfma_f32_16x16x32_f16(ap, bv, o[ni], 0, 0, 0);
        }
      }
    }
    __syncthreads();
  }

#pragma unroll
  for (int r = 0; r < 4; ++r) {
    float inv = 1.0f / lrun[r];
#pragma unroll
    for (int ni = 0; ni < 4; ++ni) {
      AWV[((size_t)(b * 1024 + iw + quad * 4 + r)) * 1024 + h * 64 + ni * 16 + l15] =
          f2bf(o[ni][r] * inv);
    }
  }
}

// ---------------------------------------------------------------------------
extern "C" void kernel_launch(void* const* d_in, const int* in_sizes, int n_in,
                              void* d_out, int out_size, void* d_ws, size_t ws_size,
                              hipStream_t stream) {
  const void* input_ = d_in[0];
  const void* pose   = d_in[1];
  const void* memry  = d_in[2];
  const void* ubias  = d_in[3];
  const void* vbias  = d_in[4];
  const void* Wkv    = d_in[5];
  const void* Wq     = d_in[6];
  const void* Wp     = d_in[7];
  const void* Wout   = d_in[8];
  // d_in[9] (mask) unused: mask is j <= i + 1024, computed analytically.

  char* base = (char*)d_ws;
  size_t off = 0;
  auto carve = [&](size_t bytes) {
    void* r = base + off;
    off += (bytes + 255) & ~(size_t)255;
    return r;
  };
  int* dflag = (int*)carve(256);
  u16* Kb    = (u16*)carve((size_t)4 * 2048 * 1024 * 2);   // K  [b][t][hd] bf16
  u16* VT    = (u16*)carve((size_t)1024 * 4 * 2048 * 2);   // V^T [hd][b][t] fp16
  u16* QU    = (u16*)carve((size_t)4 * 1024 * 1024 * 2);
  u16* QV    = (u16*)carve((size_t)4 * 1024 * 1024 * 2);
  u16* Pb    = (u16*)carve((size_t)2048 * 1024 * 2);
  u16* AWVb  = (u16*)carve((size_t)4 * 1024 * 1024 * 2);
  u16* WkvT  = (u16*)carve((size_t)2048 * 1024 * 2);
  u16* WqT   = (u16*)carve((size_t)1024 * 1024 * 2);
  u16* WpT   = (u16*)carve((size_t)1024 * 1024 * 2);
  u16* WoutT = (u16*)carve((size_t)1024 * 1024 * 2);
  u16* inpB  = (u16*)carve((size_t)4 * 1024 * 1024 * 2);
  u16* memB  = (u16*)carve((size_t)4 * 1024 * 1024 * 2);
  u16* poseB = (u16*)carve((size_t)2048 * 1024 * 2);

  detect_dtype<<<1, 64, 0, stream>>>((const unsigned*)input_, dflag);
  convert_all<<<dim3(4096, 1, 3), 256, 0, stream>>>(
      input_, memry, pose, inpB, memB, poseB, dflag);
  transpose_all<<<dim3(64, 32, 4), dim3(32, 8), 0, stream>>>(
      Wkv, Wq, Wp, Wout, WkvT, WqT, WpT, WoutT, dflag);

  // kv = [memory;input] @ W_kv  (M=8192, N=2048, K=1024) — K->Kb bf16, V->VT fp16^T
  gemm_bt<<<dim3(16, 64, 1), 256, 0, stream>>>(
      nullptr, 0, 0, 0, WkvT, 1024, 0, 0, Kb, 1024, 0, 1024, 5,
      memB, inpB, nullptr, nullptr, VT, dflag);
  // q = input @ W_q, fused +u/+v -> QU, QV  (M=4096, N=1024, K=1024)
  gemm_bt<<<dim3(8, 32, 1), 256, 0, stream>>>(
      inpB, 1024, 0, 0, WqT, 1024, 0, 0, QU, 1024, 0, 1024, 1,
      nullptr, nullptr, ubias, vbias, QV, dflag);
  // p = pos_embs @ W_p  (M=2048, N=1024, K=1024)
  gemm_bt<<<dim3(8, 16, 1), 256, 0, stream>>>(
      poseB, 1024, 0, 0, WpT, 1024, 0, 0, Pb, 1024, 0, 1024, 0,
      nullptr, nullptr, nullptr, nullptr, nullptr, dflag);

  // fused attention, all 16 heads in one dispatch (1024 blocks)
  attn_fused<<<dim3(16, 16, 4), 256, 0, stream>>>(QU, QV, Kb, VT, Pb, AWVb);

  // out = awv @ W_out  (M=4096, N=1024, K=1024), output dtype per flag
  gemm_bt<<<dim3(8, 32, 1), 256, 0, stream>>>(
      AWVb, 1024, 0, 0, WoutT, 1024, 0, 0, d_out, 1024, 0, 1024, 3,
      nullptr, nullptr, nullptr, nullptr, nullptr, dflag);
}